// Round 3
// baseline (269.938 us; speedup 1.0000x reference)
//
#include <hip/hip_runtime.h>
#include <hip/hip_bf16.h>
#include <math.h>

#define E_N 4096
#define PI_F 3.14159265358979323846f
#define ATH 0.08726646259971647f   /* radians(5.0), rounds to same f32 as jax */

// angle counting-sort bins
#define AB_N 2048
#define AB_SCALE 651.8986469f      /* 2048/pi */
#define BWINP1 60                  /* window bins [bp, bp+59]; need ceil(ATH*AB_SCALE)=57, +3 margin */

// distance histograms (two-level selection: resolution W2 = 3.8e-5)
#define NB1 2048
#define NB2 2048
#define RMAX 160.0f
#define W1 (RMAX / (float)NB1)       /* 0.078125 */
#define SCALE1 ((float)NB1 / RMAX)   /* 12.8 */
#define W2 (W1 / (float)NB2)
#define SCALE2 ((float)NB2 / W1)

// workspace layout (bytes) — total 155,712 B (proven ws_size >= 163,912)
#define OFF_ANG    0        /* 4096 f32 */
#define OFF_NX     16384
#define OFF_NY     32768
#define OFF_C      49152
#define OFF_MX     65536
#define OFF_MY     81920
#define OFF_SIDX   98304    /* 4096 u32: sorted slot -> original edge */
#define OFF_BSTART 114688   /* 2048 u32: first slot of each angle bin */
#define OFF_H1     122880   /* 2048 u32 */
#define OFF_H2     131072   /* 3*2048 u32 (24KB); reused as partial[1024] doubles in passC */
#define OFF_ST     155648   /* 16 u32: [0..2] bins, [3..5] ranks, [6] n, f[8] mu, f[9] margin */

__device__ __forceinline__ int bin_of(float a) {
    int b = (int)(a * AB_SCALE);
    return b < 0 ? 0 : (b > AB_N - 1 ? AB_N - 1 : b);
}

// forward-window candidate count for sorted slot p (conservative superset;
// exact circ test filters per pair)
__device__ __forceinline__ unsigned win_cnt(int p, float ap,
                                            const unsigned* __restrict__ bstart) {
    int bw = bin_of(ap) + BWINP1;
    if (bw >= AB_N) bw -= AB_N;
    unsigned end_excl = bstart[bw];
    return (end_excl + E_N - 1u - (unsigned)p) & (E_N - 1u);
}

// ---- fused: dtype detect + edge prep + counting sort (1 block) -------------
__global__ __launch_bounds__(1024) void init_sort(
    const void* __restrict__ posv, const int* __restrict__ eidx,
    float* __restrict__ angA, float* __restrict__ nxA, float* __restrict__ nyA,
    float* __restrict__ cA, float* __restrict__ mxA, float* __restrict__ myA,
    unsigned* __restrict__ sidx, unsigned* __restrict__ bstart,
    unsigned* __restrict__ h1)
{
    __shared__ unsigned cnt[AB_N];     // bin counts -> cursors
    __shared__ unsigned scan[1024];
    __shared__ unsigned flag;
    int tid = threadIdx.x;
    if (tid == 0) flag = 0u;
    cnt[tid] = 0u; cnt[tid + 1024] = 0u;
    h1[tid] = 0u; h1[tid + 1024] = 0u;     // zero coarse hist for passA
    __syncthreads();

    // phase 1: dtype detect (f32 low-mantissa halves look like huge bf16s)
    const unsigned short* ph = (const unsigned short*)posv;
    unsigned f = 0;
#pragma unroll
    for (int k = 0; k < 8; ++k) {
        unsigned short v = ph[tid + k * 1024];
        if (((v >> 7) & 0xFFu) >= 137u) f = 1u;
    }
    if (f) atomicOr(&flag, 1u);
    __syncthreads();
    bool isf32 = (flag != 0u);

    // phase 2: per-edge geometry + angle-bin count
    int lb[4];
#pragma unroll
    for (int k = 0; k < 4; ++k) {
        int e = tid + k * 1024;
        int s = eidx[e], d = eidx[E_N + e];
        float px, py, qx, qy;
        if (isf32) {
            const float* pf = (const float*)posv;
            px = pf[2*s]; py = pf[2*s+1]; qx = pf[2*d]; qy = pf[2*d+1];
        } else {
            const __hip_bfloat16* pb = (const __hip_bfloat16*)posv;
            px = __bfloat162float(pb[2*s]); py = __bfloat162float(pb[2*s+1]);
            qx = __bfloat162float(pb[2*d]); qy = __bfloat162float(pb[2*d+1]);
        }
        float vx = qx - px, vy = qy - py;
        float len = fmaxf(sqrtf(vx*vx + vy*vy), 1e-8f);
        float dx = vx / len, dy = vy / len;
        float a = fmodf(atan2f(dy, dx), PI_F);
        if (a < 0.0f) a += PI_F;          // python floor-mod -> [0, pi)
        float nx = -dy, ny = dx;
        angA[e] = a;
        nxA[e] = nx; nyA[e] = ny;
        cA[e]  = px * nx + py * ny;
        mxA[e] = (px + qx) * 0.5f;
        myA[e] = (py + qy) * 0.5f;
        int b = bin_of(a);
        lb[k] = b;
        atomicAdd(&cnt[b], 1u);
    }
    __syncthreads();

    // phase 3: exclusive scan over 2048 bins (1024 threads, 2 bins each)
    unsigned c0 = cnt[2*tid], c1 = cnt[2*tid+1];
    unsigned s2 = c0 + c1;
    scan[tid] = s2;
    __syncthreads();
    for (int off = 1; off < 1024; off <<= 1) {
        unsigned v = (tid >= off) ? scan[tid - off] : 0u;
        __syncthreads();
        scan[tid] += v;
        __syncthreads();
    }
    unsigned excl = scan[tid] - s2;
    bstart[2*tid]   = excl;
    bstart[2*tid+1] = excl + c0;
    cnt[2*tid]   = excl;          // reuse as cursors
    cnt[2*tid+1] = excl + c0;
    __syncthreads();

    // phase 4: scatter (order within bin arbitrary — exact tests downstream)
#pragma unroll
    for (int k = 0; k < 4; ++k) {
        int e = tid + k * 1024;
        unsigned pos = atomicAdd(&cnt[lb[k]], 1u);
        sidx[pos] = (unsigned)e;
    }
}

// shared candidate-pair macro body: computes d, sets `accepted`
#define PAIR_PROLOGUE(p_, lane_, stride_)                                      \
    unsigned oe = sidx[p_];                                                    \
    float ap = angA[oe];                                                       \
    unsigned wc = win_cnt(p_, ap, bstart);                                     \
    for (unsigned t = lane_; t < wc; t += stride_) {                           \
        unsigned q = ((unsigned)(p_) + 1u + t) & (E_N - 1u);                   \
        unsigned oq = sidx[q];                                                 \
        float aq = angA[oq];                                                   \
        float df = aq - ap;                                                    \
        float fa = (df >= 0.0f) ? df : df + PI_F;                              \
        float da = fabsf(df);                                                  \
        float circ = fminf(da, PI_F - da);                                     \
        bool own = (fa == 0.0f) ? (q > (unsigned)(p_)) : (fa < 1.0f);          \
        if (circ <= ATH && own) {                                              \
            unsigned is = (oe < oq) ? oe : oq;                                 \
            unsigned ib = oe + oq - is;                                        \
            float d = fabsf(nxA[is]*mxA[ib] + nyA[is]*myA[ib] - cA[is]);

#define PAIR_EPILOGUE } }

// ---- pass A: coarse histogram ----------------------------------------------
__global__ __launch_bounds__(64) void passA(
    const float* __restrict__ angA, const float* __restrict__ nxA,
    const float* __restrict__ nyA, const float* __restrict__ cA,
    const float* __restrict__ mxA, const float* __restrict__ myA,
    const unsigned* __restrict__ sidx, const unsigned* __restrict__ bstart,
    unsigned* __restrict__ h1)
{
    int p = blockIdx.x;
    PAIR_PROLOGUE(p, threadIdx.x, 64u)
        int b = (int)(d * SCALE1); if (b > NB1 - 1) b = NB1 - 1;
        atomicAdd(&h1[b], 1u);
    PAIR_EPILOGUE
}

// ---- refine 1: n, ranks, coarse bin per rank; zero h2 ----------------------
__global__ __launch_bounds__(256) void refine1(const unsigned* __restrict__ h1,
                                               unsigned* __restrict__ st,
                                               unsigned* __restrict__ h2) {
    __shared__ unsigned a[256];
    __shared__ unsigned rk[3];
    __shared__ unsigned ntot;
    int tid = threadIdx.x;
    for (int k = tid; k < 3 * NB2; k += 256) h2[k] = 0u;
    unsigned loc[8];
    unsigned s = 0;
#pragma unroll
    for (int k = 0; k < 8; ++k) { loc[k] = h1[tid * 8 + k]; s += loc[k]; }
    a[tid] = s;
    __syncthreads();
    for (int off = 1; off < 256; off <<= 1) {
        unsigned v = (tid >= off) ? a[tid - off] : 0u;
        __syncthreads();
        a[tid] += v;
        __syncthreads();
    }
    if (tid == 255) {
        unsigned n = a[255];
        ntot = n; st[6] = n;
        long long q1 = (long long)(n / 4) - 1; if (q1 < 0) q1 = 0;
        long long q3 = (3LL * (long long)n) / 4;
        if (q3 > (long long)n - 1) q3 = (long long)n - 1;
        if (q3 < 0) q3 = 0;
        rk[0] = (unsigned)q1; rk[1] = n / 2; rk[2] = (unsigned)q3;
    }
    __syncthreads();
    unsigned excl = a[tid] - s;
    for (int t = 0; t < 3; ++t) {
        unsigned r = rk[t];
        if (ntot > 0 && r >= excl && r < excl + s) {
            unsigned cum = excl;
#pragma unroll
            for (int k = 0; k < 8; ++k) {
                unsigned c2 = cum + loc[k];
                if (r < c2) { st[t] = (unsigned)(tid * 8 + k); st[3 + t] = r - cum; break; }
                cum = c2;
            }
        }
    }
}

// ---- pass B: sub-histograms of selected coarse bins ------------------------
__global__ __launch_bounds__(64) void passB(
    const float* __restrict__ angA, const float* __restrict__ nxA,
    const float* __restrict__ nyA, const float* __restrict__ cA,
    const float* __restrict__ mxA, const float* __restrict__ myA,
    const unsigned* __restrict__ sidx, const unsigned* __restrict__ bstart,
    const unsigned* __restrict__ st, unsigned* __restrict__ h2)
{
    int p = blockIdx.x;
    int tb0 = (int)st[0], tb1 = (int)st[1], tb2 = (int)st[2];
    PAIR_PROLOGUE(p, threadIdx.x, 64u)
        int b = (int)(d * SCALE1); if (b > NB1 - 1) b = NB1 - 1;
        if (b == tb0 || b == tb1 || b == tb2) {
            float lo = (float)b * W1;
            int sb = (int)((d - lo) * SCALE2);
            sb = sb < 0 ? 0 : (sb > NB2 - 1 ? NB2 - 1 : sb);
            if (b == tb0) atomicAdd(&h2[0 * NB2 + sb], 1u);
            if (b == tb1) atomicAdd(&h2[1 * NB2 + sb], 1u);
            if (b == tb2) atomicAdd(&h2[2 * NB2 + sb], 1u);
        }
    PAIR_EPILOGUE
}

// ---- refine 2: quantile values -> mu, margin -------------------------------
__global__ __launch_bounds__(256) void refine2(const unsigned* __restrict__ h2,
                                               unsigned* __restrict__ st) {
    __shared__ unsigned a[256];
    __shared__ float vv[3];
    int tid = threadIdx.x;
    for (int t = 0; t < 3; ++t) {
        const unsigned* h = h2 + t * NB2;
        unsigned loc[8];
        unsigned s = 0;
#pragma unroll
        for (int k = 0; k < 8; ++k) { loc[k] = h[tid * 8 + k]; s += loc[k]; }
        a[tid] = s;
        __syncthreads();
        for (int off = 1; off < 256; off <<= 1) {
            unsigned v = (tid >= off) ? a[tid - off] : 0u;
            __syncthreads();
            a[tid] += v;
            __syncthreads();
        }
        unsigned total = a[255];
        unsigned excl = a[tid] - s;
        unsigned r = st[3 + t];
        if (total == 0) {
            if (tid == 0) vv[t] = (float)st[t] * W1 + 0.5f * W1;
        } else {
            if (r >= total) r = total - 1;
            if (r >= excl && r < excl + s) {
                unsigned cum = excl;
#pragma unroll
                for (int k = 0; k < 8; ++k) {
                    unsigned c2 = cum + loc[k];
                    if (r < c2) {
                        vv[t] = (float)st[t] * W1 + ((float)(tid * 8 + k) + 0.5f) * W2;
                        break;
                    }
                    cum = c2;
                }
            }
        }
        __syncthreads();
    }
    if (tid == 0) {
        unsigned n = st[6];
        float* stf = (float*)st;
        if (n == 0) { stf[8] = 0.0f; stf[9] = 0.0f; }
        else {
            float iqr = fmaxf(vv[2] - vv[0], 1e-6f);
            stf[8] = vv[1];
            stf[9] = 0.75f * iqr;    /* iqr * 0.5 * 1.5 */
        }
    }
}

// ---- pass C: hinge sum (4 slots per 256-thread block) ----------------------
__global__ __launch_bounds__(256) void passC(
    const float* __restrict__ angA, const float* __restrict__ nxA,
    const float* __restrict__ nyA, const float* __restrict__ cA,
    const float* __restrict__ mxA, const float* __restrict__ myA,
    const unsigned* __restrict__ sidx, const unsigned* __restrict__ bstart,
    const unsigned* __restrict__ st, double* __restrict__ partial)
{
    const float* stf = (const float*)st;
    float mu = stf[8], margin = stf[9];
    int w = threadIdx.x >> 6, lane = threadIdx.x & 63;
    int p = blockIdx.x * 4 + w;
    double acc = 0.0;
    PAIR_PROLOGUE(p, (unsigned)lane, 64u)
        acc += (double)fmaxf(fabsf(d - mu) - margin, 0.0f);
    PAIR_EPILOGUE
    for (int off = 32; off > 0; off >>= 1) acc += __shfl_down(acc, off, 64);
    __shared__ double ws4[4];
    if (lane == 0) ws4[w] = acc;
    __syncthreads();
    if (threadIdx.x == 0) partial[blockIdx.x] = ws4[0] + ws4[1] + ws4[2] + ws4[3];
}

__global__ __launch_bounds__(256) void finalize(const double* __restrict__ partial,
                                                const unsigned* __restrict__ st,
                                                unsigned* __restrict__ out) {
    __shared__ double r[256];
    int tid = threadIdx.x;
    double acc = 0.0;
    for (int k = tid; k < 1024; k += 256) acc += partial[k];
    r[tid] = acc;
    __syncthreads();
    for (int off = 128; off > 0; off >>= 1) {
        if (tid < off) r[tid] += r[tid + off];
        __syncthreads();
    }
    if (tid == 0) {
        unsigned n = st[6];
        double denom = n ? (double)n : 1.0;
        float loss = (float)(r[0] / denom);
        __hip_bfloat16 h = __float2bfloat16(loss);
        unsigned short b = *(unsigned short*)&h;
        out[0] = ((unsigned)b << 16) | (unsigned)b;   // dtype-hedged scalar write
    }
}

extern "C" void kernel_launch(void* const* d_in, const int* in_sizes, int n_in,
                              void* d_out, int out_size, void* d_ws, size_t ws_size,
                              hipStream_t stream) {
    const void* pos = d_in[0];
    const int* eidx = (const int*)d_in[2];   // adjacency (d_in[1]) unused

    char* ws = (char*)d_ws;
    float*    angA   = (float*)(ws + OFF_ANG);
    float*    nxA    = (float*)(ws + OFF_NX);
    float*    nyA    = (float*)(ws + OFF_NY);
    float*    cA     = (float*)(ws + OFF_C);
    float*    mxA    = (float*)(ws + OFF_MX);
    float*    myA    = (float*)(ws + OFF_MY);
    unsigned* sidx   = (unsigned*)(ws + OFF_SIDX);
    unsigned* bstart = (unsigned*)(ws + OFF_BSTART);
    unsigned* h1     = (unsigned*)(ws + OFF_H1);
    unsigned* h2     = (unsigned*)(ws + OFF_H2);
    unsigned* st     = (unsigned*)(ws + OFF_ST);
    double*   partial = (double*)(ws + OFF_H2);   // reuses h2 region after refine2

    init_sort<<<1, 1024, 0, stream>>>(pos, eidx, angA, nxA, nyA, cA, mxA, myA,
                                      sidx, bstart, h1);
    passA<<<E_N, 64, 0, stream>>>(angA, nxA, nyA, cA, mxA, myA, sidx, bstart, h1);
    refine1<<<1, 256, 0, stream>>>(h1, st, h2);
    passB<<<E_N, 64, 0, stream>>>(angA, nxA, nyA, cA, mxA, myA, sidx, bstart, st, h2);
    refine2<<<1, 256, 0, stream>>>(h2, st);
    passC<<<E_N / 4, 256, 0, stream>>>(angA, nxA, nyA, cA, mxA, myA, sidx, bstart,
                                       st, partial);
    finalize<<<1, 256, 0, stream>>>(partial, st, (unsigned*)d_out);
}

// Round 4
// 203.777 us; speedup vs baseline: 1.3247x; 1.3247x over previous
//
#include <hip/hip_runtime.h>
#include <hip/hip_bf16.h>
#include <math.h>

#define E_N 4096
#define PI_F 3.14159265358979323846f
#define ATH 0.08726646259971647f   /* radians(5.0), rounds to same f32 as jax */

// angle counting-sort bins
#define AB_N 2048
#define AB_SCALE 651.8986469f      /* 2048/pi */
#define BWINP1 60                  /* window bins [bp, bp+59]; need ceil(ATH*AB_SCALE)=57, +3 margin */

// distance histograms (two-level selection: resolution W2 = 3.8e-5)
#define NB1 2048
#define NB2 2048
#define RMAX 160.0f
#define W1 (RMAX / (float)NB1)       /* 0.078125 */
#define SCALE1 ((float)NB1 / RMAX)   /* 12.8 */
#define W2 (W1 / (float)NB2)
#define SCALE2 ((float)NB2 / W1)

// workspace layout (bytes) — total <= 155,712 B (proven ws_size >= 163,912)
#define OFF_ANG    0        /* 4096 f32 */
#define OFF_NX     16384
#define OFF_NY     32768
#define OFF_C      49152
#define OFF_MX     65536
#define OFF_MY     81920
#define OFF_SIDX   98304    /* 4096 u32: sorted slot -> original edge */
#define OFF_BSTART 114688   /* 2048 u32: first slot of each angle bin */
#define OFF_H1     122880   /* 2048 u32 */
#define OFF_H2     131072   /* 3*2048 u32 (24KB); reused as partial[64] doubles in passC */
#define OFF_ST     155648   /* 16 u32: [0..2] bins, [3..5] ranks, [6] n, f[8] mu, f[9] margin */

__device__ __forceinline__ int bin_of(float a) {
    int b = (int)(a * AB_SCALE);
    return b < 0 ? 0 : (b > AB_N - 1 ? AB_N - 1 : b);
}

// forward-window candidate count for sorted slot p (conservative superset;
// exact circ test filters per pair)
__device__ __forceinline__ unsigned win_cnt(int p, float ap,
                                            const unsigned* __restrict__ bstart) {
    int bw = bin_of(ap) + BWINP1;
    if (bw >= AB_N) bw -= AB_N;
    unsigned end_excl = bstart[bw];
    return (end_excl + E_N - 1u - (unsigned)p) & (E_N - 1u);
}

// ---- fused: dtype detect + edge prep + counting sort (1 block) -------------
__global__ __launch_bounds__(1024) void init_sort(
    const void* __restrict__ posv, const int* __restrict__ eidx,
    float* __restrict__ angA, float* __restrict__ nxA, float* __restrict__ nyA,
    float* __restrict__ cA, float* __restrict__ mxA, float* __restrict__ myA,
    unsigned* __restrict__ sidx, unsigned* __restrict__ bstart,
    unsigned* __restrict__ h1)
{
    __shared__ unsigned cnt[AB_N];     // bin counts -> cursors
    __shared__ unsigned scan[1024];
    __shared__ unsigned flag;
    int tid = threadIdx.x;
    if (tid == 0) flag = 0u;
    cnt[tid] = 0u; cnt[tid + 1024] = 0u;
    h1[tid] = 0u; h1[tid + 1024] = 0u;     // zero coarse hist for passA
    __syncthreads();

    // phase 1: dtype detect (f32 low-mantissa halves look like huge bf16s)
    const unsigned short* ph = (const unsigned short*)posv;
    unsigned f = 0;
#pragma unroll
    for (int k = 0; k < 8; ++k) {
        unsigned short v = ph[tid + k * 1024];
        if (((v >> 7) & 0xFFu) >= 137u) f = 1u;
    }
    if (f) atomicOr(&flag, 1u);
    __syncthreads();
    bool isf32 = (flag != 0u);

    // phase 2: per-edge geometry + angle-bin count
    int lb[4];
#pragma unroll
    for (int k = 0; k < 4; ++k) {
        int e = tid + k * 1024;
        int s = eidx[e], d = eidx[E_N + e];
        float px, py, qx, qy;
        if (isf32) {
            const float* pf = (const float*)posv;
            px = pf[2*s]; py = pf[2*s+1]; qx = pf[2*d]; qy = pf[2*d+1];
        } else {
            const __hip_bfloat16* pb = (const __hip_bfloat16*)posv;
            px = __bfloat162float(pb[2*s]); py = __bfloat162float(pb[2*s+1]);
            qx = __bfloat162float(pb[2*d]); qy = __bfloat162float(pb[2*d+1]);
        }
        float vx = qx - px, vy = qy - py;
        float len = fmaxf(sqrtf(vx*vx + vy*vy), 1e-8f);
        float dx = vx / len, dy = vy / len;
        float a = fmodf(atan2f(dy, dx), PI_F);
        if (a < 0.0f) a += PI_F;          // python floor-mod -> [0, pi)
        float nx = -dy, ny = dx;
        angA[e] = a;
        nxA[e] = nx; nyA[e] = ny;
        cA[e]  = px * nx + py * ny;
        mxA[e] = (px + qx) * 0.5f;
        myA[e] = (py + qy) * 0.5f;
        int b = bin_of(a);
        lb[k] = b;
        atomicAdd(&cnt[b], 1u);
    }
    __syncthreads();

    // phase 3: exclusive scan over 2048 bins (1024 threads, 2 bins each)
    unsigned c0 = cnt[2*tid], c1 = cnt[2*tid+1];
    unsigned s2 = c0 + c1;
    scan[tid] = s2;
    __syncthreads();
    for (int off = 1; off < 1024; off <<= 1) {
        unsigned v = (tid >= off) ? scan[tid - off] : 0u;
        __syncthreads();
        scan[tid] += v;
        __syncthreads();
    }
    unsigned excl = scan[tid] - s2;
    bstart[2*tid]   = excl;
    bstart[2*tid+1] = excl + c0;
    cnt[2*tid]   = excl;          // reuse as cursors
    cnt[2*tid+1] = excl + c0;
    __syncthreads();

    // phase 4: scatter (order within bin arbitrary — exact tests downstream)
#pragma unroll
    for (int k = 0; k < 4; ++k) {
        int e = tid + k * 1024;
        unsigned pos = atomicAdd(&cnt[lb[k]], 1u);
        sidx[pos] = (unsigned)e;
    }
}

// candidate-pair enumeration for sorted slot p_, lanes lane_ of stride_:
// computes exact reference mask; d = perpendicular distance with the lower
// ORIGINAL index as the line (matches reference asymmetry)
#define PAIR_PROLOGUE(p_, lane_, stride_)                                      \
    unsigned oe = sidx[p_];                                                    \
    float ap = angA[oe];                                                       \
    unsigned wc = win_cnt(p_, ap, bstart);                                     \
    for (unsigned t = lane_; t < wc; t += stride_) {                           \
        unsigned q = ((unsigned)(p_) + 1u + t) & (E_N - 1u);                   \
        unsigned oq = sidx[q];                                                 \
        float aq = angA[oq];                                                   \
        float df = aq - ap;                                                    \
        float fa = (df >= 0.0f) ? df : df + PI_F;                              \
        float da = fabsf(df);                                                  \
        float circ = fminf(da, PI_F - da);                                     \
        bool own = (fa == 0.0f) ? (q > (unsigned)(p_)) : (fa < 1.0f);          \
        if (circ <= ATH && own) {                                              \
            unsigned is = (oe < oq) ? oe : oq;                                 \
            unsigned ib = oe + oq - is;                                        \
            float d = fabsf(nxA[is]*mxA[ib] + nyA[is]*myA[ib] - cA[is]);

#define PAIR_EPILOGUE } }

// ---- pass A: coarse histogram, LDS-privatized (64 blocks x 256) ------------
__global__ __launch_bounds__(256) void passA(
    const float* __restrict__ angA, const float* __restrict__ nxA,
    const float* __restrict__ nyA, const float* __restrict__ cA,
    const float* __restrict__ mxA, const float* __restrict__ myA,
    const unsigned* __restrict__ sidx, const unsigned* __restrict__ bstart,
    unsigned* __restrict__ h1)
{
    __shared__ unsigned sh[NB1];
    int tid = threadIdx.x;
    for (int k = tid; k < NB1; k += 256) sh[k] = 0u;
    __syncthreads();
    int w = tid >> 6, lane = tid & 63;
#pragma unroll 1
    for (int i = 0; i < 16; ++i) {
        int p = blockIdx.x * 64 + i * 4 + w;
        PAIR_PROLOGUE(p, (unsigned)lane, 64u)
            int b = (int)(d * SCALE1); if (b > NB1 - 1) b = NB1 - 1;
            atomicAdd(&sh[b], 1u);
        PAIR_EPILOGUE
    }
    __syncthreads();
    for (int k = tid; k < NB1; k += 256) {
        unsigned v = sh[k];
        if (v) atomicAdd(&h1[k], v);
    }
}

// ---- refine 1: n, ranks, coarse bin per rank; zero h2 ----------------------
__global__ __launch_bounds__(256) void refine1(const unsigned* __restrict__ h1,
                                               unsigned* __restrict__ st,
                                               unsigned* __restrict__ h2) {
    __shared__ unsigned a[256];
    __shared__ unsigned rk[3];
    __shared__ unsigned ntot;
    int tid = threadIdx.x;
    for (int k = tid; k < 3 * NB2; k += 256) h2[k] = 0u;
    unsigned loc[8];
    unsigned s = 0;
#pragma unroll
    for (int k = 0; k < 8; ++k) { loc[k] = h1[tid * 8 + k]; s += loc[k]; }
    a[tid] = s;
    __syncthreads();
    for (int off = 1; off < 256; off <<= 1) {
        unsigned v = (tid >= off) ? a[tid - off] : 0u;
        __syncthreads();
        a[tid] += v;
        __syncthreads();
    }
    if (tid == 255) {
        unsigned n = a[255];
        ntot = n; st[6] = n;
        long long q1 = (long long)(n / 4) - 1; if (q1 < 0) q1 = 0;
        long long q3 = (3LL * (long long)n) / 4;
        if (q3 > (long long)n - 1) q3 = (long long)n - 1;
        if (q3 < 0) q3 = 0;
        rk[0] = (unsigned)q1; rk[1] = n / 2; rk[2] = (unsigned)q3;
    }
    __syncthreads();
    unsigned excl = a[tid] - s;
    for (int t = 0; t < 3; ++t) {
        unsigned r = rk[t];
        if (ntot > 0 && r >= excl && r < excl + s) {
            unsigned cum = excl;
#pragma unroll
            for (int k = 0; k < 8; ++k) {
                unsigned c2 = cum + loc[k];
                if (r < c2) { st[t] = (unsigned)(tid * 8 + k); st[3 + t] = r - cum; break; }
                cum = c2;
            }
        }
    }
}

// ---- pass B: sub-histograms of selected coarse bins, LDS-privatized --------
__global__ __launch_bounds__(256) void passB(
    const float* __restrict__ angA, const float* __restrict__ nxA,
    const float* __restrict__ nyA, const float* __restrict__ cA,
    const float* __restrict__ mxA, const float* __restrict__ myA,
    const unsigned* __restrict__ sidx, const unsigned* __restrict__ bstart,
    const unsigned* __restrict__ st, unsigned* __restrict__ h2)
{
    __shared__ unsigned sh[3 * NB2];
    int tid = threadIdx.x;
    for (int k = tid; k < 3 * NB2; k += 256) sh[k] = 0u;
    __syncthreads();
    int tb0 = (int)st[0], tb1 = (int)st[1], tb2 = (int)st[2];
    int w = tid >> 6, lane = tid & 63;
#pragma unroll 1
    for (int i = 0; i < 16; ++i) {
        int p = blockIdx.x * 64 + i * 4 + w;
        PAIR_PROLOGUE(p, (unsigned)lane, 64u)
            int b = (int)(d * SCALE1); if (b > NB1 - 1) b = NB1 - 1;
            if (b == tb0 || b == tb1 || b == tb2) {
                float lo = (float)b * W1;
                int sb = (int)((d - lo) * SCALE2);
                sb = sb < 0 ? 0 : (sb > NB2 - 1 ? NB2 - 1 : sb);
                if (b == tb0) atomicAdd(&sh[0 * NB2 + sb], 1u);
                if (b == tb1) atomicAdd(&sh[1 * NB2 + sb], 1u);
                if (b == tb2) atomicAdd(&sh[2 * NB2 + sb], 1u);
            }
        PAIR_EPILOGUE
    }
    __syncthreads();
    for (int k = tid; k < 3 * NB2; k += 256) {
        unsigned v = sh[k];
        if (v) atomicAdd(&h2[k], v);
    }
}

// ---- refine 2: quantile values -> mu, margin -------------------------------
__global__ __launch_bounds__(256) void refine2(const unsigned* __restrict__ h2,
                                               unsigned* __restrict__ st) {
    __shared__ unsigned a[256];
    __shared__ float vv[3];
    int tid = threadIdx.x;
    for (int t = 0; t < 3; ++t) {
        const unsigned* h = h2 + t * NB2;
        unsigned loc[8];
        unsigned s = 0;
#pragma unroll
        for (int k = 0; k < 8; ++k) { loc[k] = h[tid * 8 + k]; s += loc[k]; }
        a[tid] = s;
        __syncthreads();
        for (int off = 1; off < 256; off <<= 1) {
            unsigned v = (tid >= off) ? a[tid - off] : 0u;
            __syncthreads();
            a[tid] += v;
            __syncthreads();
        }
        unsigned total = a[255];
        unsigned excl = a[tid] - s;
        unsigned r = st[3 + t];
        if (total == 0) {
            if (tid == 0) vv[t] = (float)st[t] * W1 + 0.5f * W1;
        } else {
            if (r >= total) r = total - 1;
            if (r >= excl && r < excl + s) {
                unsigned cum = excl;
#pragma unroll
                for (int k = 0; k < 8; ++k) {
                    unsigned c2 = cum + loc[k];
                    if (r < c2) {
                        vv[t] = (float)st[t] * W1 + ((float)(tid * 8 + k) + 0.5f) * W2;
                        break;
                    }
                    cum = c2;
                }
            }
        }
        __syncthreads();
    }
    if (tid == 0) {
        unsigned n = st[6];
        float* stf = (float*)st;
        if (n == 0) { stf[8] = 0.0f; stf[9] = 0.0f; }
        else {
            float iqr = fmaxf(vv[2] - vv[0], 1e-6f);
            stf[8] = vv[1];
            stf[9] = 0.75f * iqr;    /* iqr * 0.5 * 1.5 */
        }
    }
}

// ---- pass C: hinge sum (64 blocks x 256, one double per block) -------------
__global__ __launch_bounds__(256) void passC(
    const float* __restrict__ angA, const float* __restrict__ nxA,
    const float* __restrict__ nyA, const float* __restrict__ cA,
    const float* __restrict__ mxA, const float* __restrict__ myA,
    const unsigned* __restrict__ sidx, const unsigned* __restrict__ bstart,
    const unsigned* __restrict__ st, double* __restrict__ partial)
{
    const float* stf = (const float*)st;
    float mu = stf[8], margin = stf[9];
    int tid = threadIdx.x;
    int w = tid >> 6, lane = tid & 63;
    double acc = 0.0;
#pragma unroll 1
    for (int i = 0; i < 16; ++i) {
        int p = blockIdx.x * 64 + i * 4 + w;
        PAIR_PROLOGUE(p, (unsigned)lane, 64u)
            acc += (double)fmaxf(fabsf(d - mu) - margin, 0.0f);
        PAIR_EPILOGUE
    }
    for (int off = 32; off > 0; off >>= 1) acc += __shfl_down(acc, off, 64);
    __shared__ double ws4[4];
    if (lane == 0) ws4[w] = acc;
    __syncthreads();
    if (tid == 0) partial[blockIdx.x] = ws4[0] + ws4[1] + ws4[2] + ws4[3];
}

__global__ __launch_bounds__(64) void finalize(const double* __restrict__ partial,
                                               const unsigned* __restrict__ st,
                                               unsigned* __restrict__ out) {
    int tid = threadIdx.x;
    double acc = partial[tid];          // 64 partials, one per lane
    for (int off = 32; off > 0; off >>= 1) acc += __shfl_down(acc, off, 64);
    if (tid == 0) {
        unsigned n = st[6];
        double denom = n ? (double)n : 1.0;
        float loss = (float)(acc / denom);
        __hip_bfloat16 h = __float2bfloat16(loss);
        unsigned short b = *(unsigned short*)&h;
        out[0] = ((unsigned)b << 16) | (unsigned)b;   // dtype-hedged scalar write
    }
}

extern "C" void kernel_launch(void* const* d_in, const int* in_sizes, int n_in,
                              void* d_out, int out_size, void* d_ws, size_t ws_size,
                              hipStream_t stream) {
    const void* pos = d_in[0];
    const int* eidx = (const int*)d_in[2];   // adjacency (d_in[1]) unused

    char* ws = (char*)d_ws;
    float*    angA   = (float*)(ws + OFF_ANG);
    float*    nxA    = (float*)(ws + OFF_NX);
    float*    nyA    = (float*)(ws + OFF_NY);
    float*    cA     = (float*)(ws + OFF_C);
    float*    mxA    = (float*)(ws + OFF_MX);
    float*    myA    = (float*)(ws + OFF_MY);
    unsigned* sidx   = (unsigned*)(ws + OFF_SIDX);
    unsigned* bstart = (unsigned*)(ws + OFF_BSTART);
    unsigned* h1     = (unsigned*)(ws + OFF_H1);
    unsigned* h2     = (unsigned*)(ws + OFF_H2);
    unsigned* st     = (unsigned*)(ws + OFF_ST);
    double*   partial = (double*)(ws + OFF_H2);   // reuses h2 region after refine2

    init_sort<<<1, 1024, 0, stream>>>(pos, eidx, angA, nxA, nyA, cA, mxA, myA,
                                      sidx, bstart, h1);
    passA<<<64, 256, 0, stream>>>(angA, nxA, nyA, cA, mxA, myA, sidx, bstart, h1);
    refine1<<<1, 256, 0, stream>>>(h1, st, h2);
    passB<<<64, 256, 0, stream>>>(angA, nxA, nyA, cA, mxA, myA, sidx, bstart, st, h2);
    refine2<<<1, 256, 0, stream>>>(h2, st);
    passC<<<64, 256, 0, stream>>>(angA, nxA, nyA, cA, mxA, myA, sidx, bstart,
                                  st, partial);
    finalize<<<1, 64, 0, stream>>>(partial, st, (unsigned*)d_out);
}